// Round 2
// baseline (327.827 us; speedup 1.0000x reference)
//
#include <hip/hip_runtime.h>
#include <hip/hip_bf16.h>

// MHSA: B=8, N=2048, C=256, H=4, d=64. Inputs/outputs FLOAT32 (per reference).
// k1: QKV GEMM (X@Wqkv^T+b, f32 in, bf16 MFMA) -> Q[bh][n][d], K[bh][n][d], Vt[bh][d][n] (bf16 ws)
// k2: flash attention per (bh, 64-row Q tile) -> O[b][n][h*d] (bf16 ws)
// k3: proj GEMM (O@Wp^T+b) -> out (f32)

typedef __bf16 bf16x8 __attribute__((ext_vector_type(8)));
typedef float f32x4 __attribute__((ext_vector_type(4)));

#define MFMA16x16(a, b, c) __builtin_amdgcn_mfma_f32_16x16x32_bf16((a), (b), (c), 0, 0, 0)

__device__ __forceinline__ bf16x8 ldg8(const __bf16* p) {
    return *reinterpret_cast<const bf16x8*>(p);
}

// load 8 consecutive f32, convert to bf16x8
__device__ __forceinline__ bf16x8 cvt8(const float* p) {
    const f32x4 u = *reinterpret_cast<const f32x4*>(p);
    const f32x4 v = *reinterpret_cast<const f32x4*>(p + 4);
    bf16x8 r;
    r[0] = (__bf16)u[0]; r[1] = (__bf16)u[1]; r[2] = (__bf16)u[2]; r[3] = (__bf16)u[3];
    r[4] = (__bf16)v[0]; r[5] = (__bf16)v[1]; r[6] = (__bf16)v[2]; r[7] = (__bf16)v[3];
    return r;
}

// ---------------- QKV projection GEMM ----------------
// X [16384,256] (f32) @ Wq[768,256]^T + bq -> scatter Q/K/Vt (bf16)
__global__ __launch_bounds__(256) void qkv_gemm(
    const float* __restrict__ X, const float* __restrict__ Wq,
    const float* __restrict__ bq, __bf16* __restrict__ Qw,
    __bf16* __restrict__ Kw, __bf16* __restrict__ Vt)
{
    const int tid = threadIdx.x;
    const int w = tid >> 6, lane = tid & 63;
    const int lo = lane & 15, hi = lane >> 4;
    const int n0 = blockIdx.x * 64;            // output-feature tile
    const int m0 = blockIdx.y * 128 + w * 32;  // row tile (wave gets 32 rows)

    f32x4 acc[2][4] = {};

    const float* xp = X + (m0 + lo) * 256 + hi * 8;
    const float* wp = Wq + (n0 + lo) * 256 + hi * 8;
    #pragma unroll
    for (int k = 0; k < 256; k += 32) {
        bf16x8 a0 = cvt8(xp + k);
        bf16x8 a1 = cvt8(xp + 16 * 256 + k);
        bf16x8 b0 = cvt8(wp + k);
        bf16x8 b1 = cvt8(wp + 16 * 256 + k);
        bf16x8 b2 = cvt8(wp + 32 * 256 + k);
        bf16x8 b3 = cvt8(wp + 48 * 256 + k);
        acc[0][0] = MFMA16x16(a0, b0, acc[0][0]);
        acc[0][1] = MFMA16x16(a0, b1, acc[0][1]);
        acc[0][2] = MFMA16x16(a0, b2, acc[0][2]);
        acc[0][3] = MFMA16x16(a0, b3, acc[0][3]);
        acc[1][0] = MFMA16x16(a1, b0, acc[1][0]);
        acc[1][1] = MFMA16x16(a1, b1, acc[1][1]);
        acc[1][2] = MFMA16x16(a1, b2, acc[1][2]);
        acc[1][3] = MFMA16x16(a1, b3, acc[1][3]);
    }

    #pragma unroll
    for (int ni = 0; ni < 4; ++ni) {
        const int col = n0 + ni * 16 + lo;
        const float bias = bq[col];
        #pragma unroll
        for (int mi = 0; mi < 2; ++mi) {
            #pragma unroll
            for (int r = 0; r < 4; ++r) {
                const int row = m0 + mi * 16 + hi * 4 + r;
                const __bf16 hv = (__bf16)(acc[mi][ni][r] + bias);
                const int bb = row >> 11, n = row & 2047;
                const int d = col & 63;
                if (col < 256) {
                    const int h = col >> 6;
                    Qw[((bb * 4 + h) * 2048 + n) * 64 + d] = hv;
                } else if (col < 512) {
                    const int h = (col - 256) >> 6;
                    Kw[((bb * 4 + h) * 2048 + n) * 64 + d] = hv;
                } else {
                    const int h = (col - 512) >> 6;
                    Vt[((bb * 4 + h) * 64 + d) * 2048 + n] = hv;
                }
            }
        }
    }
}

// ---------------- flash attention ----------------
// grid (N/64, B*H). Block: 4 waves x 16 Q-rows. KV tiles of 64, online softmax.
__global__ __launch_bounds__(256) void attn_kernel(
    const __bf16* __restrict__ Qw, const __bf16* __restrict__ Kw,
    const __bf16* __restrict__ Vt, __bf16* __restrict__ Ow)
{
    __shared__ __align__(16) unsigned char Plds[64 * 128];  // P tile bf16, swizzled

    const int tid = threadIdx.x;
    const int w = tid >> 6, lane = tid & 63;
    const int lo = lane & 15, hi = lane >> 4;
    const int bh = blockIdx.y;
    const int q0 = blockIdx.x * 64 + w * 16;

    // Q fragments in registers (A-operand; lane holds Q[q0+lo][hi*8 + s*32 + j])
    const __bf16* Qp = Qw + (bh * 2048 + q0 + lo) * 64 + hi * 8;
    const bf16x8 qf0 = ldg8(Qp);
    const bf16x8 qf1 = ldg8(Qp + 32);

    const __bf16* Kbase = Kw + bh * 2048 * 64;
    const __bf16* Vbase = Vt + bh * 64 * 2048;

    f32x4 oacc[4] = {};
    float mr[4] = {-1e30f, -1e30f, -1e30f, -1e30f};
    float lr[4] = {0.f, 0.f, 0.f, 0.f};
    const float c2 = 0.125f * 1.44269504088896340736f;  // SCALE * log2(e)

    for (int t = 0; t < 32; ++t) {
        const int kv0 = t * 64;
        // ---- S = Q K^T  (S[q][kv], C-layout: row q=hi*4+r, col kv=f*16+lo)
        f32x4 sacc[4] = {};
        const __bf16* Kp = Kbase + (kv0 + lo) * 64 + hi * 8;
        #pragma unroll
        for (int f = 0; f < 4; ++f) {
            bf16x8 k0 = ldg8(Kp + f * 16 * 64);
            bf16x8 k1 = ldg8(Kp + f * 16 * 64 + 32);
            sacc[f] = MFMA16x16(qf0, k0, sacc[f]);
            sacc[f] = MFMA16x16(qf1, k1, sacc[f]);
        }
        // ---- online softmax (log2 domain)
        float alpha[4];
        float p[4][4];  // [f][r]
        #pragma unroll
        for (int r = 0; r < 4; ++r) {
            float s0 = sacc[0][r] * c2, s1 = sacc[1][r] * c2;
            float s2 = sacc[2][r] * c2, s3 = sacc[3][r] * c2;
            float mx = fmaxf(fmaxf(s0, s1), fmaxf(s2, s3));
            mx = fmaxf(mx, __shfl_xor(mx, 1));
            mx = fmaxf(mx, __shfl_xor(mx, 2));
            mx = fmaxf(mx, __shfl_xor(mx, 4));
            mx = fmaxf(mx, __shfl_xor(mx, 8));
            const float mnew = fmaxf(mr[r], mx);
            const float a = exp2f(mr[r] - mnew);
            mr[r] = mnew;
            alpha[r] = a;
            const float p0 = exp2f(s0 - mnew), p1 = exp2f(s1 - mnew);
            const float p2 = exp2f(s2 - mnew), p3 = exp2f(s3 - mnew);
            p[0][r] = p0; p[1][r] = p1; p[2][r] = p2; p[3][r] = p3;
            float rs = p0 + p1 + p2 + p3;
            rs += __shfl_xor(rs, 1);
            rs += __shfl_xor(rs, 2);
            rs += __shfl_xor(rs, 4);
            rs += __shfl_xor(rs, 8);
            lr[r] = lr[r] * a + rs;
        }
        #pragma unroll
        for (int df = 0; df < 4; ++df)
            #pragma unroll
            for (int r = 0; r < 4; ++r)
                oacc[df][r] *= alpha[r];

        // ---- P -> LDS (bf16, XOR-swizzled rows; wave touches only its own 16 rows)
        #pragma unroll
        for (int f = 0; f < 4; ++f) {
            #pragma unroll
            for (int r = 0; r < 4; ++r) {
                const int q = w * 16 + hi * 4 + r;
                const int kv = f * 16 + lo;
                const int byteoff = (q * 128 + kv * 2) ^ ((q & 7) << 4);
                *reinterpret_cast<__bf16*>(&Plds[byteoff]) = (__bf16)p[f][r];
            }
        }
        // ---- O += P V   (A = P from LDS, B = V^T rows = contiguous)
        #pragma unroll
        for (int ks = 0; ks < 2; ++ks) {
            const int qrow = w * 16 + lo;
            const int byteoff = (qrow * 128 + ks * 64 + hi * 16) ^ ((qrow & 7) << 4);
            const bf16x8 pa = *reinterpret_cast<const bf16x8*>(&Plds[byteoff]);
            const __bf16* Vp = Vbase + lo * 2048 + kv0 + ks * 32 + hi * 8;
            #pragma unroll
            for (int df = 0; df < 4; ++df) {
                bf16x8 vb = ldg8(Vp + df * 16 * 2048);
                oacc[df] = MFMA16x16(pa, vb, oacc[df]);
            }
        }
    }

    // ---- epilogue: O[b][n][h*64+d]  (bf16 workspace)
    const int bb = bh >> 2, h = bh & 3;
    float inv[4];
    #pragma unroll
    for (int r = 0; r < 4; ++r) inv[r] = 1.0f / lr[r];
    #pragma unroll
    for (int df = 0; df < 4; ++df) {
        #pragma unroll
        for (int r = 0; r < 4; ++r) {
            const int q = q0 + hi * 4 + r;
            const int d = df * 16 + lo;
            Ow[(bb * 2048 + q) * 256 + h * 64 + d] = (__bf16)(oacc[df][r] * inv[r]);
        }
    }
}

// ---------------- output projection GEMM ----------------
// A = Ow (bf16 ws), Wp f32 -> cvt, out f32
__global__ __launch_bounds__(256) void proj_gemm(
    const __bf16* __restrict__ A, const float* __restrict__ Wp,
    const float* __restrict__ bp, float* __restrict__ out)
{
    const int tid = threadIdx.x;
    const int w = tid >> 6, lane = tid & 63;
    const int lo = lane & 15, hi = lane >> 4;
    const int n0 = blockIdx.x * 64;
    const int m0 = blockIdx.y * 128 + w * 32;

    f32x4 acc[2][4] = {};
    const __bf16* ap = A + (m0 + lo) * 256 + hi * 8;
    const float*  wp = Wp + (n0 + lo) * 256 + hi * 8;
    #pragma unroll
    for (int k = 0; k < 256; k += 32) {
        bf16x8 a0 = ldg8(ap + k);
        bf16x8 a1 = ldg8(ap + 16 * 256 + k);
        bf16x8 b0 = cvt8(wp + k);
        bf16x8 b1 = cvt8(wp + 16 * 256 + k);
        bf16x8 b2 = cvt8(wp + 32 * 256 + k);
        bf16x8 b3 = cvt8(wp + 48 * 256 + k);
        acc[0][0] = MFMA16x16(a0, b0, acc[0][0]);
        acc[0][1] = MFMA16x16(a0, b1, acc[0][1]);
        acc[0][2] = MFMA16x16(a0, b2, acc[0][2]);
        acc[0][3] = MFMA16x16(a0, b3, acc[0][3]);
        acc[1][0] = MFMA16x16(a1, b0, acc[1][0]);
        acc[1][1] = MFMA16x16(a1, b1, acc[1][1]);
        acc[1][2] = MFMA16x16(a1, b2, acc[1][2]);
        acc[1][3] = MFMA16x16(a1, b3, acc[1][3]);
    }
    #pragma unroll
    for (int ni = 0; ni < 4; ++ni) {
        const int col = n0 + ni * 16 + lo;
        const float bias = bp[col];
        #pragma unroll
        for (int mi = 0; mi < 2; ++mi) {
            #pragma unroll
            for (int r = 0; r < 4; ++r) {
                const int row = m0 + mi * 16 + hi * 4 + r;
                out[row * 256 + col] = acc[mi][ni][r] + bias;
            }
        }
    }
}

extern "C" void kernel_launch(void* const* d_in, const int* in_sizes, int n_in,
                              void* d_out, int out_size, void* d_ws, size_t ws_size,
                              hipStream_t stream)
{
    const float* x  = (const float*)d_in[0];   // [8,2048,256] f32
    const float* Wq = (const float*)d_in[1];   // [768,256] f32
    const float* bq = (const float*)d_in[2];   // [768] f32
    const float* Wp = (const float*)d_in[3];   // [256,256] f32
    const float* bp = (const float*)d_in[4];   // [256] f32

    __bf16* ws = (__bf16*)d_ws;
    const size_t SZ = (size_t)32 * 2048 * 64;  // 4,194,304 elems per tensor
    __bf16* Qw = ws;
    __bf16* Kw = Qw + SZ;
    __bf16* Vt = Kw + SZ;
    __bf16* Ow = Vt + SZ;

    qkv_gemm<<<dim3(12, 128), 256, 0, stream>>>(x, Wq, bq, Qw, Kw, Vt);
    attn_kernel<<<dim3(32, 32), 256, 0, stream>>>(Qw, Kw, Vt, Ow);
    proj_gemm<<<dim3(4, 128), 256, 0, stream>>>(Ow, Wp, bp, (float*)d_out);
}

// Round 3
// 189.673 us; speedup vs baseline: 1.7284x; 1.7284x over previous
//
#include <hip/hip_runtime.h>
#include <hip/hip_bf16.h>

// MHSA: B=8, N=2048, C=256, H=4, d=64. Inputs/outputs FLOAT32.
// k0: cvt_all  : X, W_qkv, W_proj f32 -> bf16 workspace copies
// k1: qkv_gemm : Xb@Wqb^T+b -> Q(prescaled)[bh][n][d], K[bh][n][d], Vt[bh][d][n]
// k2: attn     : swapped-QK^T flash attention, 32x32 MFMA, in-register softmax
// k3: proj_gemm: Ow@Wpb^T+b -> out (f32)

typedef __bf16 bf16x8 __attribute__((ext_vector_type(8)));
typedef float f32x4 __attribute__((ext_vector_type(4)));
typedef float f32x16 __attribute__((ext_vector_type(16)));
typedef unsigned u32x2 __attribute__((ext_vector_type(2)));

#define MFMA16(a, b, c) __builtin_amdgcn_mfma_f32_16x16x32_bf16((a), (b), (c), 0, 0, 0)
#define MFMA32(a, b, c) __builtin_amdgcn_mfma_f32_32x32x16_bf16((a), (b), (c), 0, 0, 0)

// SCALE * log2(e)
#define C2 0.18033688011112042f

__device__ __forceinline__ bf16x8 ldg8(const __bf16* p) {
    return *reinterpret_cast<const bf16x8*>(p);
}

__device__ __forceinline__ unsigned pk2(float a, float b) {
    __bf16 x = (__bf16)a, y = (__bf16)b;
    unsigned short ux = __builtin_bit_cast(unsigned short, x);
    unsigned short uy = __builtin_bit_cast(unsigned short, y);
    return (unsigned)ux | ((unsigned)uy << 16);
}

// ---------------- f32 -> bf16 conversion ----------------
// groups of 8 elems: X 524288, Wq 24576, Wp 8192  (total 557056 = 2176*256)
__global__ __launch_bounds__(256) void cvt_all(
    const float* __restrict__ X, const float* __restrict__ Wq,
    const float* __restrict__ Wp, __bf16* __restrict__ Xb,
    __bf16* __restrict__ Wqb, __bf16* __restrict__ Wpb)
{
    const int g = blockIdx.x * 256 + threadIdx.x;
    const float* src;
    __bf16* dst;
    int off;
    if (g < 524288)      { src = X;  dst = Xb;  off = g; }
    else if (g < 548864) { src = Wq; dst = Wqb; off = g - 524288; }
    else                 { src = Wp; dst = Wpb; off = g - 548864; }
    const float* p = src + (size_t)off * 8;
    const f32x4 a = *reinterpret_cast<const f32x4*>(p);
    const f32x4 b = *reinterpret_cast<const f32x4*>(p + 4);
    bf16x8 r;
    r[0] = (__bf16)a[0]; r[1] = (__bf16)a[1]; r[2] = (__bf16)a[2]; r[3] = (__bf16)a[3];
    r[4] = (__bf16)b[0]; r[5] = (__bf16)b[1]; r[6] = (__bf16)b[2]; r[7] = (__bf16)b[3];
    *reinterpret_cast<bf16x8*>(dst + (size_t)off * 8) = r;
}

// ---------------- QKV projection GEMM (bf16) ----------------
__global__ __launch_bounds__(256) void qkv_gemm(
    const __bf16* __restrict__ X, const __bf16* __restrict__ Wq,
    const float* __restrict__ bq, __bf16* __restrict__ Qw,
    __bf16* __restrict__ Kw, __bf16* __restrict__ Vt)
{
    const int tid = threadIdx.x;
    const int w = tid >> 6, lane = tid & 63;
    const int lo = lane & 15, hi = lane >> 4;
    const int n0 = blockIdx.x * 64;
    const int m0 = blockIdx.y * 128 + w * 32;

    f32x4 acc[2][4] = {};
    const __bf16* xp = X + (m0 + lo) * 256 + hi * 8;
    const __bf16* wp = Wq + (n0 + lo) * 256 + hi * 8;
    #pragma unroll
    for (int k = 0; k < 256; k += 32) {
        bf16x8 a0 = ldg8(xp + k);
        bf16x8 a1 = ldg8(xp + 16 * 256 + k);
        bf16x8 b0 = ldg8(wp + k);
        bf16x8 b1 = ldg8(wp + 16 * 256 + k);
        bf16x8 b2 = ldg8(wp + 32 * 256 + k);
        bf16x8 b3 = ldg8(wp + 48 * 256 + k);
        acc[0][0] = MFMA16(a0, b0, acc[0][0]);
        acc[0][1] = MFMA16(a0, b1, acc[0][1]);
        acc[0][2] = MFMA16(a0, b2, acc[0][2]);
        acc[0][3] = MFMA16(a0, b3, acc[0][3]);
        acc[1][0] = MFMA16(a1, b0, acc[1][0]);
        acc[1][1] = MFMA16(a1, b1, acc[1][1]);
        acc[1][2] = MFMA16(a1, b2, acc[1][2]);
        acc[1][3] = MFMA16(a1, b3, acc[1][3]);
    }

    #pragma unroll
    for (int ni = 0; ni < 4; ++ni) {
        const int col = n0 + ni * 16 + lo;
        const float bias = bq[col];
        const float scale = (col < 256) ? C2 : 1.0f;   // pre-scale Q by SCALE*log2e
        #pragma unroll
        for (int mi = 0; mi < 2; ++mi) {
            #pragma unroll
            for (int r = 0; r < 4; ++r) {
                const int row = m0 + mi * 16 + hi * 4 + r;
                const __bf16 hv = (__bf16)((acc[mi][ni][r] + bias) * scale);
                const int bb = row >> 11, n = row & 2047;
                const int d = col & 63;
                if (col < 256) {
                    const int h = col >> 6;
                    Qw[((bb * 4 + h) * 2048 + n) * 64 + d] = hv;
                } else if (col < 512) {
                    const int h = (col - 256) >> 6;
                    Kw[((bb * 4 + h) * 2048 + n) * 64 + d] = hv;
                } else {
                    const int h = (col - 512) >> 6;
                    Vt[((bb * 4 + h) * 64 + d) * 2048 + n] = hv;
                }
            }
        }
    }
}

// ---------------- flash attention, swapped QK^T, 32x32 MFMA ----------------
// grid (16, 32): block = 4 waves, each wave owns 32 q-rows. No LDS.
// S^T = mfma32(K-frag, Q-frag): lane owns q = l&31; 32 kv values lane-local.
__global__ __launch_bounds__(256) void attn_kernel(
    const __bf16* __restrict__ Qw, const __bf16* __restrict__ Kw,
    const __bf16* __restrict__ Vt, __bf16* __restrict__ Ow)
{
    const int tid = threadIdx.x;
    const int w = tid >> 6, lane = tid & 63;
    const int l31 = lane & 31, hi5 = lane >> 5;
    const int bh = blockIdx.y;
    const int q = blockIdx.x * 128 + w * 32 + l31;

    // Q as B-operand frags: Qf[db] -> Q[q][db*16 + hi5*8 + j]
    const __bf16* Qp = Qw + (bh * 2048 + q) * 64 + hi5 * 8;
    bf16x8 Qf[4];
    #pragma unroll
    for (int db = 0; db < 4; ++db) Qf[db] = ldg8(Qp + db * 16);

    const __bf16* Kbase = Kw + bh * 2048 * 64;
    const __bf16* Vbase = Vt + bh * 64 * 2048;

    f32x16 oacc0 = (f32x16)0.0f, oacc1 = (f32x16)0.0f;  // O^T d 0-31 / 32-63
    float mr = -1e30f, lr = 0.0f;

    for (int t = 0; t < 32; ++t) {
        const int kv0 = t * 64;

        // ---- S^T = K Q^T (already in log2 domain; Q pre-scaled)
        f32x16 s0 = (f32x16)0.0f, s1 = (f32x16)0.0f;
        const __bf16* Kp = Kbase + (kv0 + l31) * 64 + hi5 * 8;
        #pragma unroll
        for (int db = 0; db < 4; ++db) {
            bf16x8 k0 = ldg8(Kp + db * 16);
            bf16x8 k1 = ldg8(Kp + 32 * 64 + db * 16);
            s0 = MFMA32(k0, Qf[db], s0);
            s1 = MFMA32(k1, Qf[db], s1);
        }

        // ---- V^T frags (issued early; independent of softmax)
        bf16x8 Vf[2][2][2];  // [dblk][kh][b2]
        const __bf16* Vp = Vbase + l31 * 2048 + kv0 + hi5 * 8;
        #pragma unroll
        for (int dblk = 0; dblk < 2; ++dblk)
            #pragma unroll
            for (int kh = 0; kh < 2; ++kh)
                #pragma unroll
                for (int b2 = 0; b2 < 2; ++b2)
                    Vf[dblk][kh][b2] = ldg8(Vp + dblk * 32 * 2048 + kh * 32 + b2 * 16);

        // ---- online softmax: all 32 kv values lane-local, 2 shfls total
        float a0 = fmaxf(fmaxf(s0[0], s0[1]), fmaxf(s0[2], s0[3]));
        float a1 = fmaxf(fmaxf(s0[4], s0[5]), fmaxf(s0[6], s0[7]));
        float a2 = fmaxf(fmaxf(s0[8], s0[9]), fmaxf(s0[10], s0[11]));
        float a3 = fmaxf(fmaxf(s0[12], s0[13]), fmaxf(s0[14], s0[15]));
        float b0 = fmaxf(fmaxf(s1[0], s1[1]), fmaxf(s1[2], s1[3]));
        float b1 = fmaxf(fmaxf(s1[4], s1[5]), fmaxf(s1[6], s1[7]));
        float b2m = fmaxf(fmaxf(s1[8], s1[9]), fmaxf(s1[10], s1[11]));
        float b3 = fmaxf(fmaxf(s1[12], s1[13]), fmaxf(s1[14], s1[15]));
        float mx = fmaxf(fmaxf(fmaxf(a0, a1), fmaxf(a2, a3)),
                         fmaxf(fmaxf(b0, b1), fmaxf(b2m, b3)));
        mx = fmaxf(mx, __shfl_xor(mx, 32));
        const float mnew = fmaxf(mr, mx);
        const float alpha = exp2f(mr - mnew);
        mr = mnew;

        float p0[16], p1[16];
        #pragma unroll
        for (int i = 0; i < 16; ++i) p0[i] = exp2f(s0[i] - mnew);
        #pragma unroll
        for (int i = 0; i < 16; ++i) p1[i] = exp2f(s1[i] - mnew);

        float r0 = 0.f, r1 = 0.f, r2 = 0.f, r3 = 0.f;
        #pragma unroll
        for (int i = 0; i < 4; ++i) {
            r0 += p0[i]; r1 += p0[4 + i]; r2 += p0[8 + i]; r3 += p0[12 + i];
            r0 += p1[i]; r1 += p1[4 + i]; r2 += p1[8 + i]; r3 += p1[12 + i];
        }
        float rs = (r0 + r1) + (r2 + r3);
        rs += __shfl_xor(rs, 32);
        lr = lr * alpha + rs;

        #pragma unroll
        for (int i = 0; i < 16; ++i) { oacc0[i] *= alpha; oacc1[i] *= alpha; }

        // ---- P^T -> bf16 B-frags via cvt_pk + permlane32_swap; PV MFMA
        // regs [8*b2 .. 8*b2+7] of p{kh} cover kv16-block b2 of kh.
        // swap(W0,W2), swap(W1,W3) -> B-frag dwords 0..3 for both hi-halves.
#define PVSTEP(PARR, KH)                                                      \
        {                                                                     \
            _Pragma("unroll")                                                 \
            for (int bb2 = 0; bb2 < 2; ++bb2) {                               \
                unsigned w0 = pk2(PARR[8 * bb2 + 0], PARR[8 * bb2 + 1]);      \
                unsigned w1 = pk2(PARR[8 * bb2 + 2], PARR[8 * bb2 + 3]);      \
                unsigned w2 = pk2(PARR[8 * bb2 + 4], PARR[8 * bb2 + 5]);      \
                unsigned w3 = pk2(PARR[8 * bb2 + 6], PARR[8 * bb2 + 7]);      \
                asm volatile("v_permlane32_swap_b32 %0, %1" : "+v"(w0), "+v"(w2)); \
                asm volatile("v_permlane32_swap_b32 %0, %1" : "+v"(w1), "+v"(w3)); \
                union { unsigned u[4]; bf16x8 v; } pb;                        \
                pb.u[0] = w0; pb.u[1] = w1; pb.u[2] = w2; pb.u[3] = w3;       \
                oacc0 = MFMA32(Vf[0][KH][bb2], pb.v, oacc0);                  \
                oacc1 = MFMA32(Vf[1][KH][bb2], pb.v, oacc1);                  \
            }                                                                 \
        }
        PVSTEP(p0, 0)
        PVSTEP(p1, 1)
#undef PVSTEP
    }

    // ---- epilogue: O[b][q][h*64+d], packed 8B stores
    const float invl = 1.0f / lr;
    const int bb = bh >> 2, h = bh & 3;
    __bf16* Op = Ow + ((size_t)(bb * 2048 + q)) * 256 + h * 64 + hi5 * 4;
#define EPI(OACC, DBLK)                                                       \
    {                                                                         \
        _Pragma("unroll")                                                     \
        for (int rq = 0; rq < 4; ++rq) {                                      \
            u32x2 st;                                                         \
            st.x = pk2(OACC[rq * 4 + 0] * invl, OACC[rq * 4 + 1] * invl);     \
            st.y = pk2(OACC[rq * 4 + 2] * invl, OACC[rq * 4 + 3] * invl);     \
            *reinterpret_cast<u32x2*>(Op + DBLK * 32 + rq * 8) = st;          \
        }                                                                     \
    }
    EPI(oacc0, 0)
    EPI(oacc1, 1)
#undef EPI
}

// ---------------- output projection GEMM ----------------
__global__ __launch_bounds__(256) void proj_gemm(
    const __bf16* __restrict__ A, const __bf16* __restrict__ Wp,
    const float* __restrict__ bp, float* __restrict__ out)
{
    const int tid = threadIdx.x;
    const int w = tid >> 6, lane = tid & 63;
    const int lo = lane & 15, hi = lane >> 4;
    const int n0 = blockIdx.x * 64;
    const int m0 = blockIdx.y * 128 + w * 32;

    f32x4 acc[2][4] = {};
    const __bf16* ap = A + (m0 + lo) * 256 + hi * 8;
    const __bf16* wp = Wp + (n0 + lo) * 256 + hi * 8;
    #pragma unroll
    for (int k = 0; k < 256; k += 32) {
        bf16x8 a0 = ldg8(ap + k);
        bf16x8 a1 = ldg8(ap + 16 * 256 + k);
        bf16x8 b0 = ldg8(wp + k);
        bf16x8 b1 = ldg8(wp + 16 * 256 + k);
        bf16x8 b2 = ldg8(wp + 32 * 256 + k);
        bf16x8 b3 = ldg8(wp + 48 * 256 + k);
        acc[0][0] = MFMA16(a0, b0, acc[0][0]);
        acc[0][1] = MFMA16(a0, b1, acc[0][1]);
        acc[0][2] = MFMA16(a0, b2, acc[0][2]);
        acc[0][3] = MFMA16(a0, b3, acc[0][3]);
        acc[1][0] = MFMA16(a1, b0, acc[1][0]);
        acc[1][1] = MFMA16(a1, b1, acc[1][1]);
        acc[1][2] = MFMA16(a1, b2, acc[1][2]);
        acc[1][3] = MFMA16(a1, b3, acc[1][3]);
    }
    #pragma unroll
    for (int ni = 0; ni < 4; ++ni) {
        const int col = n0 + ni * 16 + lo;
        const float bias = bp[col];
        #pragma unroll
        for (int mi = 0; mi < 2; ++mi) {
            #pragma unroll
            for (int r = 0; r < 4; ++r) {
                const int row = m0 + mi * 16 + hi * 4 + r;
                out[row * 256 + col] = acc[mi][ni][r] + bias;
            }
        }
    }
}

extern "C" void kernel_launch(void* const* d_in, const int* in_sizes, int n_in,
                              void* d_out, int out_size, void* d_ws, size_t ws_size,
                              hipStream_t stream)
{
    const float* x  = (const float*)d_in[0];   // [8,2048,256] f32
    const float* Wq = (const float*)d_in[1];   // [768,256] f32
    const float* bq = (const float*)d_in[2];   // [768] f32
    const float* Wp = (const float*)d_in[3];   // [256,256] f32
    const float* bp = (const float*)d_in[4];   // [256] f32

    __bf16* ws = (__bf16*)d_ws;
    const size_t SZ = (size_t)32 * 2048 * 64;  // 4,194,304
    __bf16* Xb  = ws;
    __bf16* Wqb = Xb + SZ;
    __bf16* Wpb = Wqb + 196608;
    __bf16* Qw  = Wpb + 65536;
    __bf16* Kw  = Qw + SZ;
    __bf16* Vt  = Kw + SZ;
    __bf16* Ow  = Xb;                          // Xb dead after qkv_gemm

    cvt_all<<<2176, 256, 0, stream>>>(x, Wq, Wp, Xb, Wqb, Wpb);
    qkv_gemm<<<dim3(12, 128), 256, 0, stream>>>(Xb, Wqb, bq, Qw, Kw, Vt);
    attn_kernel<<<dim3(16, 32), 256, 0, stream>>>(Qw, Kw, Vt, Ow);
    proj_gemm<<<dim3(4, 128), 256, 0, stream>>>(Ow, Wpb, bp, (float*)d_out);
}